// Round 2
// baseline (9347.839 us; speedup 1.0000x reference)
//
#include <hip/hip_runtime.h>
#include <math.h>

// ---------------------------------------------------------------------------
// ESABot RGAT pipeline, fp32 throughout.
//   1) feat = concat(lrelu(des@Wd+bd), ..., lrelu(newf@Wf+bf))   [N,128]
//   2) x1 = lrelu(feat@Wi+bi)                                    [N,128]
//   3) CSR build (dst-sorted edge list, packed ridx = et*N+src)
//   4) RGAT layer: dual-relation GEMM xw[r]=x@w[r]; qi/kj per-node scalars;
//      per-node wave softmax + gather-aggregate (+bias)
//   5) repeat RGAT (H=1); fused lrelu(x@Wo1+bo1)@Wo2+bo2 -> out [N,2]
// ---------------------------------------------------------------------------

// ------------------------------ generic GEMM -------------------------------
// out[r, col_off+c] = lrelu( sum_k A[r,k]*W[k,c] + bias[c], 0.01 )
// BM=64 rows/block, BK=32, 256 threads. Thread (rg,cgrp): rows rg*4..+3,
// cols cgrp*RN..+RN-1. As staged transposed [BK][BM+4] so a 4-row fragment
// is one aligned ds_read_b128. A staging float4-vectorized when K%4==0.
template<int NC, int RN>
__launch_bounds__(256)
__global__ void gemm_lrelu_k(const float* __restrict__ A, int K, int M,
                             const float* __restrict__ W,
                             const float* __restrict__ bias,
                             float* __restrict__ out, int ldo, int col_off)
{
    constexpr int BM = 64, BK = 32;
    __shared__ __align__(16) float As[BK][BM + 4];
    __shared__ __align__(16) float Bs[BK][NC];

    const int t    = threadIdx.x;
    const int m0   = blockIdx.x * BM;
    const int rg   = t & 15;
    const int cgrp = t >> 4;
    const int cb   = cgrp * RN;
    const bool act = (cb < NC);
    const bool vec = ((K & 3) == 0);

    float acc[4][RN];
#pragma unroll
    for (int i = 0; i < 4; ++i)
#pragma unroll
        for (int j = 0; j < RN; ++j) acc[i][j] = 0.f;

    const int nk = (K + BK - 1) / BK;
    for (int kt = 0; kt < nk; ++kt) {
        const int k0 = kt * BK;
        if (vec) {
            // 64x32 tile = 512 float4; 2 per thread
#pragma unroll
            for (int i = 0; i < 2; ++i) {
                int idx = t + i * 256;
                int r = idx >> 3, kq = (idx & 7) << 2;
                int gr = m0 + r, gk = k0 + kq;
                float4 v = make_float4(0.f, 0.f, 0.f, 0.f);
                if (gr < M && gk < K) v = *(const float4*)&A[(size_t)gr * K + gk];
                As[kq + 0][r] = v.x; As[kq + 1][r] = v.y;
                As[kq + 2][r] = v.z; As[kq + 3][r] = v.w;
            }
        } else {
#pragma unroll
            for (int i = 0; i < 8; ++i) {
                int idx = t + i * 256;
                int r = idx >> 5, kk = idx & 31;
                int gr = m0 + r, gk = k0 + kk;
                float v = 0.f;
                if (gr < M && gk < K) v = A[(size_t)gr * K + gk];
                As[kk][r] = v;
            }
        }
        constexpr int NB4 = BK * NC / 4;
        for (int idx = t; idx < NB4; idx += 256) {
            int k = idx / (NC / 4), c4 = (idx % (NC / 4)) * 4;
            int gk = k0 + k;
            float4 v = make_float4(0.f, 0.f, 0.f, 0.f);
            if (gk < K) v = *(const float4*)&W[(size_t)gk * NC + c4];
            *(float4*)&Bs[k][c4] = v;
        }
        __syncthreads();
        if (act) {
#pragma unroll
            for (int k = 0; k < BK; ++k) {
                float4 av = *(const float4*)&As[k][rg * 4];
                float a[4] = {av.x, av.y, av.z, av.w};
                float bv[RN];
#pragma unroll
                for (int j4 = 0; j4 < RN / 4; ++j4) {
                    float4 b = *(const float4*)&Bs[k][cb + j4 * 4];
                    bv[j4 * 4 + 0] = b.x; bv[j4 * 4 + 1] = b.y;
                    bv[j4 * 4 + 2] = b.z; bv[j4 * 4 + 3] = b.w;
                }
#pragma unroll
                for (int i = 0; i < 4; ++i)
#pragma unroll
                    for (int j = 0; j < RN; ++j)
                        acc[i][j] = fmaf(a[i], bv[j], acc[i][j]);
            }
        }
        __syncthreads();
    }
    if (act) {
        float bj[RN];
#pragma unroll
        for (int j = 0; j < RN; ++j) bj[j] = bias[cb + j];
#pragma unroll
        for (int i = 0; i < 4; ++i) {
            int r = m0 + rg * 4 + i;
            if (r < M) {
#pragma unroll
                for (int j4 = 0; j4 < RN / 4; ++j4) {
                    float4 v;
                    float o0 = acc[i][j4 * 4 + 0] + bj[j4 * 4 + 0];
                    float o1 = acc[i][j4 * 4 + 1] + bj[j4 * 4 + 1];
                    float o2 = acc[i][j4 * 4 + 2] + bj[j4 * 4 + 2];
                    float o3 = acc[i][j4 * 4 + 3] + bj[j4 * 4 + 3];
                    v.x = (o0 >= 0.f) ? o0 : 0.01f * o0;
                    v.y = (o1 >= 0.f) ? o1 : 0.01f * o1;
                    v.z = (o2 >= 0.f) ? o2 : 0.01f * o2;
                    v.w = (o3 >= 0.f) ? o3 : 0.01f * o3;
                    *(float4*)&out[(size_t)r * ldo + col_off + cb + j4 * 4] = v;
                }
            }
        }
    }
}

// --------------------------- dual-relation GEMM ----------------------------
// xw[r] = A @ W_r for r=0,1 in one pass (A tile staged once, reused for both
// relation weight matrices). K = NC = 128 fixed. No bias, no activation.
__launch_bounds__(256)
__global__ void gemm_dual_k(const float* __restrict__ A, int M,
                            const float* __restrict__ W0,
                            const float* __restrict__ W1,
                            float* __restrict__ out0,
                            float* __restrict__ out1)
{
    constexpr int BM = 64, BK = 32;
    __shared__ __align__(16) float As[BK][BM + 4];
    __shared__ __align__(16) float Bs[BK][256];

    const int t    = threadIdx.x;
    const int m0   = blockIdx.x * BM;
    const int rg   = t & 15;
    const int cgrp = t >> 4;
    const int cb   = cgrp * 16;      // 16 groups x 16 cols = 256

    float acc[4][16];
#pragma unroll
    for (int i = 0; i < 4; ++i)
#pragma unroll
        for (int j = 0; j < 16; ++j) acc[i][j] = 0.f;

#pragma unroll
    for (int kt = 0; kt < 4; ++kt) {
        const int k0 = kt * BK;
        // A tile 64x32 transposed, float4 loads
#pragma unroll
        for (int i = 0; i < 2; ++i) {
            int idx = t + i * 256;
            int r = idx >> 3, kq = (idx & 7) << 2;
            int gr = m0 + r;
            float4 v = make_float4(0.f, 0.f, 0.f, 0.f);
            if (gr < M) v = *(const float4*)&A[(size_t)gr * 128 + k0 + kq];
            As[kq + 0][r] = v.x; As[kq + 1][r] = v.y;
            As[kq + 2][r] = v.z; As[kq + 3][r] = v.w;
        }
        // B tile 32x256 (both relations): 2048 float4, 8 per thread
#pragma unroll
        for (int i = 0; i < 8; ++i) {
            int idx = t + i * 256;
            int k = idx >> 6, c4 = idx & 63;
            const float* Wp = (c4 < 32) ? W0 : W1;
            int cc = (c4 & 31) * 4;
            float4 v = *(const float4*)&Wp[(size_t)(k0 + k) * 128 + cc];
            *(float4*)&Bs[k][c4 * 4] = v;
        }
        __syncthreads();
#pragma unroll
        for (int k = 0; k < BK; ++k) {
            float4 av = *(const float4*)&As[k][rg * 4];
            float a[4] = {av.x, av.y, av.z, av.w};
            float bv[16];
#pragma unroll
            for (int j4 = 0; j4 < 4; ++j4) {
                float4 b = *(const float4*)&Bs[k][cb + j4 * 4];
                bv[j4 * 4 + 0] = b.x; bv[j4 * 4 + 1] = b.y;
                bv[j4 * 4 + 2] = b.z; bv[j4 * 4 + 3] = b.w;
            }
#pragma unroll
            for (int i = 0; i < 4; ++i)
#pragma unroll
                for (int j = 0; j < 16; ++j)
                    acc[i][j] = fmaf(a[i], bv[j], acc[i][j]);
        }
        __syncthreads();
    }
    float* dst = (cb < 128) ? out0 : out1;
    const int cc = cb & 127;
#pragma unroll
    for (int i = 0; i < 4; ++i) {
        int r = m0 + rg * 4 + i;
        if (r < M) {
#pragma unroll
            for (int j4 = 0; j4 < 4; ++j4) {
                float4 v = make_float4(acc[i][j4 * 4 + 0], acc[i][j4 * 4 + 1],
                                       acc[i][j4 * 4 + 2], acc[i][j4 * 4 + 3]);
                *(float4*)&dst[(size_t)r * 128 + cc + j4 * 4] = v;
            }
        }
    }
}

// ------------------------- fused Wo1 + lrelu + Wo2 -------------------------
// out[r,0:2] = lrelu(A[r,:]@W + bias, 0.01) @ W2 + b2.  K=NC=128.
__launch_bounds__(256)
__global__ void gemm_out_k(const float* __restrict__ A, int M,
                           const float* __restrict__ W,
                           const float* __restrict__ bias,
                           const float* __restrict__ W2,
                           const float* __restrict__ b2,
                           float* __restrict__ out)
{
    constexpr int BM = 64, BK = 32;
    __shared__ __align__(16) float As[BK][BM + 4];
    __shared__ __align__(16) float Bs[BK][128];
    __shared__ float red[16][64][2];

    const int t    = threadIdx.x;
    const int m0   = blockIdx.x * BM;
    const int rg   = t & 15;
    const int cgrp = t >> 4;
    const int cb   = cgrp * 8;

    float acc[4][8];
#pragma unroll
    for (int i = 0; i < 4; ++i)
#pragma unroll
        for (int j = 0; j < 8; ++j) acc[i][j] = 0.f;

#pragma unroll
    for (int kt = 0; kt < 4; ++kt) {
        const int k0 = kt * BK;
#pragma unroll
        for (int i = 0; i < 2; ++i) {
            int idx = t + i * 256;
            int r = idx >> 3, kq = (idx & 7) << 2;
            int gr = m0 + r;
            float4 v = make_float4(0.f, 0.f, 0.f, 0.f);
            if (gr < M) v = *(const float4*)&A[(size_t)gr * 128 + k0 + kq];
            As[kq + 0][r] = v.x; As[kq + 1][r] = v.y;
            As[kq + 2][r] = v.z; As[kq + 3][r] = v.w;
        }
#pragma unroll
        for (int i = 0; i < 4; ++i) {
            int idx = t + i * 256;
            int k = idx >> 5, c4 = (idx & 31) * 4;
            float4 v = *(const float4*)&W[(size_t)(k0 + k) * 128 + c4];
            *(float4*)&Bs[k][c4] = v;
        }
        __syncthreads();
#pragma unroll
        for (int k = 0; k < BK; ++k) {
            float4 av = *(const float4*)&As[k][rg * 4];
            float a[4] = {av.x, av.y, av.z, av.w};
            float bv[8];
#pragma unroll
            for (int j4 = 0; j4 < 2; ++j4) {
                float4 b = *(const float4*)&Bs[k][cb + j4 * 4];
                bv[j4 * 4 + 0] = b.x; bv[j4 * 4 + 1] = b.y;
                bv[j4 * 4 + 2] = b.z; bv[j4 * 4 + 3] = b.w;
            }
#pragma unroll
            for (int i = 0; i < 4; ++i)
#pragma unroll
                for (int j = 0; j < 8; ++j)
                    acc[i][j] = fmaf(a[i], bv[j], acc[i][j]);
        }
        __syncthreads();
    }
    // epilogue: lrelu + project to 2 cols, partial per thread, LDS reduce
    float w2c[8][2], bj[8];
#pragma unroll
    for (int j = 0; j < 8; ++j) {
        w2c[j][0] = W2[(cb + j) * 2 + 0];
        w2c[j][1] = W2[(cb + j) * 2 + 1];
        bj[j]     = bias[cb + j];
    }
#pragma unroll
    for (int i = 0; i < 4; ++i) {
        float p0 = 0.f, p1 = 0.f;
#pragma unroll
        for (int j = 0; j < 8; ++j) {
            float v = acc[i][j] + bj[j];
            v = (v >= 0.f) ? v : 0.01f * v;
            p0 = fmaf(v, w2c[j][0], p0);
            p1 = fmaf(v, w2c[j][1], p1);
        }
        red[cgrp][rg * 4 + i][0] = p0;
        red[cgrp][rg * 4 + i][1] = p1;
    }
    __syncthreads();
    if (t < 128) {
        int row = t >> 1, k = t & 1;
        float s = 0.f;
#pragma unroll
        for (int g = 0; g < 16; ++g) s += red[g][row][k];
        int r = m0 + row;
        if (r < M) out[(size_t)r * 2 + k] = s + b2[k];
    }
}

// ------------------------------ CSR build ----------------------------------
__global__ void count_kernel(const int* __restrict__ dst, int* __restrict__ cnt, int E)
{
    int e = blockIdx.x * 256 + threadIdx.x;
    if (e < E) atomicAdd(&cnt[dst[e]], 1);
}

// single block, 1024 threads: exclusive scan of cnt[0..n) -> off[0..n];
// also resets cnt[i] = off[i] (fill cursor).
__global__ void scan_kernel(int* __restrict__ cnt, int* __restrict__ off, int n)
{
    __shared__ int sums[1024];
    int t = threadIdx.x;
    int per = (n + 1023) >> 10;
    int lo = t * per;
    int hi = lo + per; if (hi > n) hi = n;
    int s = 0;
    for (int i = lo; i < hi; ++i) s += cnt[i];
    sums[t] = s;
    __syncthreads();
    for (int o = 1; o < 1024; o <<= 1) {
        int v = (t >= o) ? sums[t - o] : 0;
        __syncthreads();
        sums[t] += v;
        __syncthreads();
    }
    int base = (t == 0) ? 0 : sums[t - 1];
    for (int i = lo; i < hi; ++i) {
        int d = cnt[i];
        off[i] = base;
        cnt[i] = base;
        base += d;
    }
    if (t == 1023) off[n] = base;
}

// eix[slot] = et*N + src : single packed gather index (xw row / kj row).
__global__ void fill_kernel(const int* __restrict__ src, const int* __restrict__ dst,
                            const int* __restrict__ et, int* __restrict__ cur,
                            int* __restrict__ eix, int N, int E)
{
    int e = blockIdx.x * 256 + threadIdx.x;
    if (e < E) {
        int d = dst[e];
        int slot = atomicAdd(&cur[d], 1);
        eix[slot] = et[e] * N + src[e];
    }
}

// ------------------------- per-node q/k scalars -----------------------------
// qi[r,n,h] = xw[r,n,:] . q[:,h] ; kj likewise with k. One wave per (r,n) row.
template<int H>
__launch_bounds__(256)
__global__ void qk_kernel(const float* __restrict__ xw, const float* __restrict__ q,
                          const float* __restrict__ k, float* __restrict__ qi,
                          float* __restrict__ kj, int N)
{
    int w = blockIdx.x * 4 + (threadIdx.x >> 6);
    if (w >= 2 * N) return;
    int l = threadIdx.x & 63;
    const float* row = xw + (size_t)w * 128;
    float x0 = row[l], x1 = row[l + 64];
    float pq[H], pk[H];
#pragma unroll
    for (int h = 0; h < H; ++h) {
        pq[h] = x0 * q[l * H + h] + x1 * q[(l + 64) * H + h];
        pk[h] = x0 * k[l * H + h] + x1 * k[(l + 64) * H + h];
    }
#pragma unroll
    for (int m = 1; m < 64; m <<= 1) {
#pragma unroll
        for (int h = 0; h < H; ++h) {
            pq[h] += __shfl_xor(pq[h], m);
            pk[h] += __shfl_xor(pk[h], m);
        }
    }
    if (l == 0) {
#pragma unroll
        for (int h = 0; h < H; ++h) {
            qi[(size_t)w * H + h] = pq[h];
            kj[(size_t)w * H + h] = pk[h];
        }
    }
}

// ----------------------- per-node softmax + aggregate -----------------------
// One wave per destination node. H*C == 128. Lane l owns channels l and l+64.
// Fast path (d<=64): lane i owns edge i; alpha/max/sum/weights in registers,
// PV weights broadcast by __shfl. No register array is runtime-indexed.
template<int H, int C>
__launch_bounds__(256)
__global__ void rgat_node_kernel(const float* __restrict__ xw,
                                 const float* __restrict__ qi,
                                 const float* __restrict__ kj,
                                 const int* __restrict__ off,
                                 const int* __restrict__ eix,
                                 const float* __restrict__ bias,
                                 float* __restrict__ out, int N)
{
    int n = blockIdx.x * 4 + (threadIdx.x >> 6);
    if (n >= N) return;
    const int l = threadIdx.x & 63;
    const int start = off[n];
    const int d = off[n + 1] - start;
    const int c0 = l, c1 = l + 64;
    const float b0 = bias[c0], b1 = bias[c1];
    if (d == 0) {
        out[(size_t)n * 128 + c0] = b0;
        out[(size_t)n * 128 + c1] = b1;
        return;
    }
    // qi for this node, both relations (compile-time indexed only)
    float q0[H], q1[H];
#pragma unroll
    for (int h = 0; h < H; ++h) {
        q0[h] = qi[(size_t)n * H + h];
        q1[h] = qi[((size_t)N + n) * H + h];
    }
    const int h0 = c0 / C, h1 = c1 / C;

    float acc0 = 0.f, acc1 = 0.f;
    if (d <= 64) {
        const bool has = (l < d);
        int ridx = 0;
        float a[H];
        if (has) {
            ridx = eix[start + l];
            const bool r1 = (ridx >= N);
            if constexpr (H == 4) {
                float4 kv = *(const float4*)&kj[(size_t)ridx * 4];
                float kk[4] = {kv.x, kv.y, kv.z, kv.w};
#pragma unroll
                for (int h = 0; h < 4; ++h) {
                    float av = (r1 ? q1[h] : q0[h]) + kk[h];
                    a[h] = (av >= 0.f) ? av : 0.2f * av;
                }
            } else {
                float kv = kj[ridx];
                float av = (r1 ? q1[0] : q0[0]) + kv;
                a[0] = (av >= 0.f) ? av : 0.2f * av;
            }
        } else {
#pragma unroll
            for (int h = 0; h < H; ++h) a[h] = -INFINITY;
        }
        float mx[H], ex[H], sm[H], wgt[H];
#pragma unroll
        for (int h = 0; h < H; ++h) mx[h] = a[h];
#pragma unroll
        for (int m = 1; m < 64; m <<= 1)
#pragma unroll
            for (int h = 0; h < H; ++h) mx[h] = fmaxf(mx[h], __shfl_xor(mx[h], m));
#pragma unroll
        for (int h = 0; h < H; ++h) { ex[h] = has ? __expf(a[h] - mx[h]) : 0.f; sm[h] = ex[h]; }
#pragma unroll
        for (int m = 1; m < 64; m <<= 1)
#pragma unroll
            for (int h = 0; h < H; ++h) sm[h] += __shfl_xor(sm[h], m);
#pragma unroll
        for (int h = 0; h < H; ++h) wgt[h] = ex[h] / (sm[h] + 1e-16f);

        // PV: serial over edges, 2-deep pipelined row gather
        int rB = __shfl(ridx, 0);
        const float* rowB = xw + (size_t)rB * 128;
        float vB0 = rowB[c0], vB1 = rowB[c1];
        for (int i = 0; i < d; ++i) {
            float vN0 = 0.f, vN1 = 0.f;
            if (i + 1 < d) {
                int rN = __shfl(ridx, i + 1);
                const float* rowN = xw + (size_t)rN * 128;
                vN0 = rowN[c0]; vN1 = rowN[c1];
            }
            float w0_, w1_;
            if constexpr (H == 4) {
                float s0 = __shfl(wgt[0], i), s1 = __shfl(wgt[1], i);
                float s2 = __shfl(wgt[2], i), s3 = __shfl(wgt[3], i);
                w0_ = (h0 & 1) ? s1 : s0;   // h0 in {0,1}
                w1_ = (h1 & 1) ? s3 : s2;   // h1 in {2,3}
            } else {
                float s = __shfl(wgt[0], i);
                w0_ = s; w1_ = s;
            }
            acc0 = fmaf(w0_, vB0, acc0);
            acc1 = fmaf(w1_, vB1, acc1);
            vB0 = vN0; vB1 = vN1;
        }
    } else {
        // ---- generic fallback, 3 passes (rare: d > 64) ----
        float mx[H];
#pragma unroll
        for (int h = 0; h < H; ++h) mx[h] = -INFINITY;
        for (int i = l; i < d; i += 64) {
            int ridx = eix[start + i];
            const bool r1 = (ridx >= N);
            if constexpr (H == 4) {
                float4 kv = *(const float4*)&kj[(size_t)ridx * 4];
                float kk[4] = {kv.x, kv.y, kv.z, kv.w};
#pragma unroll
                for (int h = 0; h < 4; ++h) {
                    float av = (r1 ? q1[h] : q0[h]) + kk[h];
                    av = (av >= 0.f) ? av : 0.2f * av;
                    mx[h] = fmaxf(mx[h], av);
                }
            } else {
                float kv = kj[ridx];
                float av = (r1 ? q1[0] : q0[0]) + kv;
                av = (av >= 0.f) ? av : 0.2f * av;
                mx[0] = fmaxf(mx[0], av);
            }
        }
#pragma unroll
        for (int m = 1; m < 64; m <<= 1)
#pragma unroll
            for (int h = 0; h < H; ++h) mx[h] = fmaxf(mx[h], __shfl_xor(mx[h], m));
        float sm[H];
#pragma unroll
        for (int h = 0; h < H; ++h) sm[h] = 0.f;
        for (int i = l; i < d; i += 64) {
            int ridx = eix[start + i];
            const bool r1 = (ridx >= N);
            if constexpr (H == 4) {
                float4 kv = *(const float4*)&kj[(size_t)ridx * 4];
                float kk[4] = {kv.x, kv.y, kv.z, kv.w};
#pragma unroll
                for (int h = 0; h < 4; ++h) {
                    float av = (r1 ? q1[h] : q0[h]) + kk[h];
                    av = (av >= 0.f) ? av : 0.2f * av;
                    sm[h] += __expf(av - mx[h]);
                }
            } else {
                float kv = kj[ridx];
                float av = (r1 ? q1[0] : q0[0]) + kv;
                av = (av >= 0.f) ? av : 0.2f * av;
                sm[0] += __expf(av - mx[0]);
            }
        }
#pragma unroll
        for (int m = 1; m < 64; m <<= 1)
#pragma unroll
            for (int h = 0; h < H; ++h) sm[h] += __shfl_xor(sm[h], m);
        float rden[H];
#pragma unroll
        for (int h = 0; h < H; ++h) rden[h] = 1.f / (sm[h] + 1e-16f);

        // per-lane head-selected scalars (no runtime register-array indexing)
        float q0h0, q1h0, q0h1, q1h1, mxh0, mxh1, rdh0, rdh1;
        if constexpr (H == 4) {
            q0h0 = (h0 & 1) ? q0[1] : q0[0];  q1h0 = (h0 & 1) ? q1[1] : q1[0];
            q0h1 = (h1 & 1) ? q0[3] : q0[2];  q1h1 = (h1 & 1) ? q1[3] : q1[2];
            mxh0 = (h0 & 1) ? mx[1] : mx[0];  mxh1 = (h1 & 1) ? mx[3] : mx[2];
            rdh0 = (h0 & 1) ? rden[1] : rden[0];
            rdh1 = (h1 & 1) ? rden[3] : rden[2];
        } else {
            q0h0 = q0[0]; q1h0 = q1[0]; q0h1 = q0[0]; q1h1 = q1[0];
            mxh0 = mx[0]; mxh1 = mx[0]; rdh0 = rden[0]; rdh1 = rden[0];
        }
        for (int i = 0; i < d; ++i) {
            int ridx = eix[start + i];          // wave-uniform broadcast
            const bool r1 = (ridx >= N);
            float kh0, kh1;
            if constexpr (H == 4) {
                float4 kv = *(const float4*)&kj[(size_t)ridx * 4];
                kh0 = (h0 & 1) ? kv.y : kv.x;
                kh1 = (h1 & 1) ? kv.w : kv.z;
            } else {
                float kv = kj[ridx];
                kh0 = kv; kh1 = kv;
            }
            float a0 = (r1 ? q1h0 : q0h0) + kh0;
            a0 = (a0 >= 0.f) ? a0 : 0.2f * a0;
            float a1 = (r1 ? q1h1 : q0h1) + kh1;
            a1 = (a1 >= 0.f) ? a1 : 0.2f * a1;
            float w0 = __expf(a0 - mxh0) * rdh0;
            float w1 = __expf(a1 - mxh1) * rdh1;
            const float* row = xw + (size_t)ridx * 128;
            acc0 = fmaf(w0, row[c0], acc0);
            acc1 = fmaf(w1, row[c1], acc1);
        }
    }
    out[(size_t)n * 128 + c0] = acc0 + b0;
    out[(size_t)n * 128 + c1] = acc1 + b1;
}

// ---------------------------------------------------------------------------
extern "C" void kernel_launch(void* const* d_in, const int* in_sizes, int n_in,
                              void* d_out, int out_size, void* d_ws, size_t ws_size,
                              hipStream_t stream)
{
    const float* des   = (const float*)d_in[0];
    const float* tweet = (const float*)d_in[1];
    const float* nump  = (const float*)d_in[2];
    const float* catp  = (const float*)d_in[3];
    const float* newf  = (const float*)d_in[4];
    const int*   eidx  = (const int*)d_in[5];
    const int*   etype = (const int*)d_in[6];
    const float* Wd = (const float*)d_in[7],  *bd = (const float*)d_in[8];
    const float* Wt = (const float*)d_in[9],  *bt = (const float*)d_in[10];
    const float* Wn = (const float*)d_in[11], *bn = (const float*)d_in[12];
    const float* Wc = (const float*)d_in[13], *bc = (const float*)d_in[14];
    const float* Wf = (const float*)d_in[15], *bf = (const float*)d_in[16];
    const float* Wi = (const float*)d_in[17], *bi = (const float*)d_in[18];
    const float* w1 = (const float*)d_in[19], *q1 = (const float*)d_in[20];
    const float* k1 = (const float*)d_in[21], *b1 = (const float*)d_in[22];
    const float* w2 = (const float*)d_in[23], *q2 = (const float*)d_in[24];
    const float* k2 = (const float*)d_in[25], *b2 = (const float*)d_in[26];
    const float* Wo1 = (const float*)d_in[27], *bo1 = (const float*)d_in[28];
    const float* Wo2 = (const float*)d_in[29], *bo2 = (const float*)d_in[30];

    const int N = in_sizes[4];   // new_feature is [N,1]
    const int E = in_sizes[6];   // edge_type is [E]
    const int* esrc = eidx;      // edge_index[0]
    const int* edst = eidx + E;  // edge_index[1]

    // workspace carve-out (all 256B-aligned); ~109 MB total
    char* wsp = (char*)d_ws;
    size_t o = 0;
    auto alloc = [&](size_t bytes) -> char* {
        char* p = wsp + o;
        o = (o + bytes + 255) & ~(size_t)255;
        return p;
    };
    float* xA   = (float*)alloc((size_t)N * 128 * 4);
    float* xB   = (float*)alloc((size_t)N * 128 * 4);
    float* xw   = (float*)alloc((size_t)2 * N * 128 * 4);
    float* qi   = (float*)alloc((size_t)2 * N * 4 * 4);
    float* kj   = (float*)alloc((size_t)2 * N * 4 * 4);
    int*   off  = (int*)alloc((size_t)(N + 1) * 4);
    int*   cur  = (int*)alloc((size_t)N * 4);
    int*   eix  = (int*)alloc((size_t)E * 4);

    const int gM  = (N + 63) / 64;
    const int gE  = (E + 255) / 256;
    const int gN4 = (N + 3) / 4;
    const int gW2 = (2 * N + 3) / 4;

    // 1) feature linears -> xA (columns 0,28,64,76,116)
    gemm_lrelu_k<28, 4><<<gM, 256, 0, stream>>>(des,   768, N, Wd, bd, xA, 128, 0);
    gemm_lrelu_k<36, 4><<<gM, 256, 0, stream>>>(tweet, 768, N, Wt, bt, xA, 128, 28);
    gemm_lrelu_k<12, 4><<<gM, 256, 0, stream>>>(nump,  7,   N, Wn, bn, xA, 128, 64);
    gemm_lrelu_k<40, 4><<<gM, 256, 0, stream>>>(catp,  11,  N, Wc, bc, xA, 128, 76);
    gemm_lrelu_k<12, 4><<<gM, 256, 0, stream>>>(newf,  1,   N, Wf, bf, xA, 128, 116);
    // 2) input linear -> xB
    gemm_lrelu_k<128, 8><<<gM, 256, 0, stream>>>(xA, 128, N, Wi, bi, xB, 128, 0);

    // 3) CSR (dst-sorted packed edge indices); rebuilt every call
    hipMemsetAsync(cur, 0, (size_t)N * 4, stream);
    count_kernel<<<gE, 256, 0, stream>>>(edst, cur, E);
    scan_kernel<<<1, 1024, 0, stream>>>(cur, off, N);
    fill_kernel<<<gE, 256, 0, stream>>>(esrc, edst, etype, cur, eix, N, E);

    // 4) RGAT layer 1 (H=4, C=32): xB -> xA
    gemm_dual_k<<<gM, 256, 0, stream>>>(xB, N, w1, w1 + 16384, xw, xw + (size_t)N * 128);
    qk_kernel<4><<<gW2, 256, 0, stream>>>(xw, q1, k1, qi, kj, N);
    rgat_node_kernel<4, 32><<<gN4, 256, 0, stream>>>(xw, qi, kj, off, eix, b1, xA, N);

    // 5) RGAT layer 2 (H=1, C=128): xA -> xB
    gemm_dual_k<<<gM, 256, 0, stream>>>(xA, N, w2, w2 + 16384, xw, xw + (size_t)N * 128);
    qk_kernel<1><<<gW2, 256, 0, stream>>>(xw, q2, k2, qi, kj, N);
    rgat_node_kernel<1, 128><<<gN4, 256, 0, stream>>>(xw, qi, kj, off, eix, b2, xB, N);

    // 6) fused output linears -> d_out [N,2]
    gemm_out_k<<<gM, 256, 0, stream>>>(xB, N, Wo1, bo1, Wo2, bo2, (float*)d_out);
}

// Round 3
// 1048.762 us; speedup vs baseline: 8.9132x; 8.9132x over previous
//
#include <hip/hip_runtime.h>
#include <math.h>

// ---------------------------------------------------------------------------
// ESABot RGAT pipeline, fp32 throughout.
//   1) feat = concat(lrelu(des@Wd+bd), ..., lrelu(newf@Wf+bf))   [N,128]
//   2) x1 = lrelu(feat@Wi+bi)                                    [N,128]
//   3) CSR build (dst-sorted edge list, packed ridx = et*N+src)
//   4) RGAT layer: dual-relation GEMM xw[r]=x@w[r]; qi/kj per-node scalars;
//      per-node wave softmax + gather-aggregate (+bias)
//   5) repeat RGAT (H=1); fused lrelu(x@Wo1+bo1)@Wo2+bo2 -> out [N,2]
//
// R2 lesson: acc[4][16] + kt-unroll in the dual GEMM spilled (VGPR=256 cap,
// 6.5 GB scratch traffic, VALUBusy 0.9%). Dual GEMM now 512 thr / acc[4][8].
// ---------------------------------------------------------------------------

// ------------------------------ generic GEMM -------------------------------
// out[r, col_off+c] = lrelu( sum_k A[r,k]*W[k,c] + bias[c], 0.01 )
// BM=64 rows/block, BK=32, 256 threads. Thread (rg,cgrp): rows rg*4..+3,
// cols cgrp*RN..+RN-1. As staged transposed [BK][BM+4] so a 4-row fragment
// is one aligned ds_read_b128. A staging float4-vectorized when K%4==0.
template<int NC, int RN>
__launch_bounds__(256)
__global__ void gemm_lrelu_k(const float* __restrict__ A, int K, int M,
                             const float* __restrict__ W,
                             const float* __restrict__ bias,
                             float* __restrict__ out, int ldo, int col_off)
{
    constexpr int BM = 64, BK = 32;
    __shared__ __align__(16) float As[BK][BM + 4];
    __shared__ __align__(16) float Bs[BK][NC];

    const int t    = threadIdx.x;
    const int m0   = blockIdx.x * BM;
    const int rg   = t & 15;
    const int cgrp = t >> 4;
    const int cb   = cgrp * RN;
    const bool act = (cb < NC);
    const bool vec = ((K & 3) == 0);

    float acc[4][RN];
#pragma unroll
    for (int i = 0; i < 4; ++i)
#pragma unroll
        for (int j = 0; j < RN; ++j) acc[i][j] = 0.f;

    const int nk = (K + BK - 1) / BK;
    for (int kt = 0; kt < nk; ++kt) {
        const int k0 = kt * BK;
        if (vec) {
            // 64x32 tile = 512 float4; 2 per thread
#pragma unroll
            for (int i = 0; i < 2; ++i) {
                int idx = t + i * 256;
                int r = idx >> 3, kq = (idx & 7) << 2;
                int gr = m0 + r, gk = k0 + kq;
                float4 v = make_float4(0.f, 0.f, 0.f, 0.f);
                if (gr < M && gk < K) v = *(const float4*)&A[(size_t)gr * K + gk];
                As[kq + 0][r] = v.x; As[kq + 1][r] = v.y;
                As[kq + 2][r] = v.z; As[kq + 3][r] = v.w;
            }
        } else {
#pragma unroll
            for (int i = 0; i < 8; ++i) {
                int idx = t + i * 256;
                int r = idx >> 5, kk = idx & 31;
                int gr = m0 + r, gk = k0 + kk;
                float v = 0.f;
                if (gr < M && gk < K) v = A[(size_t)gr * K + gk];
                As[kk][r] = v;
            }
        }
        constexpr int NB4 = BK * NC / 4;
        for (int idx = t; idx < NB4; idx += 256) {
            int k = idx / (NC / 4), c4 = (idx % (NC / 4)) * 4;
            int gk = k0 + k;
            float4 v = make_float4(0.f, 0.f, 0.f, 0.f);
            if (gk < K) v = *(const float4*)&W[(size_t)gk * NC + c4];
            *(float4*)&Bs[k][c4] = v;
        }
        __syncthreads();
        if (act) {
#pragma unroll
            for (int k = 0; k < BK; ++k) {
                float4 av = *(const float4*)&As[k][rg * 4];
                float a[4] = {av.x, av.y, av.z, av.w};
                float bv[RN];
#pragma unroll
                for (int j4 = 0; j4 < RN / 4; ++j4) {
                    float4 b = *(const float4*)&Bs[k][cb + j4 * 4];
                    bv[j4 * 4 + 0] = b.x; bv[j4 * 4 + 1] = b.y;
                    bv[j4 * 4 + 2] = b.z; bv[j4 * 4 + 3] = b.w;
                }
#pragma unroll
                for (int i = 0; i < 4; ++i)
#pragma unroll
                    for (int j = 0; j < RN; ++j)
                        acc[i][j] = fmaf(a[i], bv[j], acc[i][j]);
            }
        }
        __syncthreads();
    }
    if (act) {
        float bj[RN];
#pragma unroll
        for (int j = 0; j < RN; ++j) bj[j] = bias[cb + j];
#pragma unroll
        for (int i = 0; i < 4; ++i) {
            int r = m0 + rg * 4 + i;
            if (r < M) {
#pragma unroll
                for (int j4 = 0; j4 < RN / 4; ++j4) {
                    float4 v;
                    float o0 = acc[i][j4 * 4 + 0] + bj[j4 * 4 + 0];
                    float o1 = acc[i][j4 * 4 + 1] + bj[j4 * 4 + 1];
                    float o2 = acc[i][j4 * 4 + 2] + bj[j4 * 4 + 2];
                    float o3 = acc[i][j4 * 4 + 3] + bj[j4 * 4 + 3];
                    v.x = (o0 >= 0.f) ? o0 : 0.01f * o0;
                    v.y = (o1 >= 0.f) ? o1 : 0.01f * o1;
                    v.z = (o2 >= 0.f) ? o2 : 0.01f * o2;
                    v.w = (o3 >= 0.f) ? o3 : 0.01f * o3;
                    *(float4*)&out[(size_t)r * ldo + col_off + cb + j4 * 4] = v;
                }
            }
        }
    }
}

// --------------------------- dual-relation GEMM ----------------------------
// xw[r] = A @ W_r for r=0,1 in one pass (A tile staged once, reused for both
// relation weight matrices). K = NC = 128 fixed. No bias, no activation.
// 512 threads, per-thread tile 4x8 (acc = 32 VGPR) -- R2's 4x16 spilled.
__launch_bounds__(512)
__global__ void gemm_dual_k(const float* __restrict__ A, int M,
                            const float* __restrict__ W0,
                            const float* __restrict__ W1,
                            float* __restrict__ out0,
                            float* __restrict__ out1)
{
    constexpr int BM = 64, BK = 32;
    __shared__ __align__(16) float As[BK][BM + 4];
    __shared__ __align__(16) float Bs[BK][256];

    const int t    = threadIdx.x;
    const int m0   = blockIdx.x * BM;
    const int rg   = t & 15;        // 16 row-groups of 4 rows
    const int cgrp = t >> 4;        // 0..31
    const int cb   = cgrp * 8;      // 32 groups x 8 cols = 256

    float acc[4][8];
#pragma unroll
    for (int i = 0; i < 4; ++i)
#pragma unroll
        for (int j = 0; j < 8; ++j) acc[i][j] = 0.f;

    for (int kt = 0; kt < 4; ++kt) {
        const int k0 = kt * BK;
        // A tile 64x32 transposed: 512 float4, 1 per thread
        {
            int r = t >> 3, kq = (t & 7) << 2;
            int gr = m0 + r;
            float4 v = make_float4(0.f, 0.f, 0.f, 0.f);
            if (gr < M) v = *(const float4*)&A[(size_t)gr * 128 + k0 + kq];
            As[kq + 0][r] = v.x; As[kq + 1][r] = v.y;
            As[kq + 2][r] = v.z; As[kq + 3][r] = v.w;
        }
        // B tile 32x256 (both relations): 2048 float4, 4 per thread
#pragma unroll
        for (int i = 0; i < 4; ++i) {
            int idx = t + i * 512;
            int k = idx >> 6, c4 = idx & 63;
            const float* Wp = (c4 < 32) ? W0 : W1;
            int cc = (c4 & 31) * 4;
            float4 v = *(const float4*)&Wp[(size_t)(k0 + k) * 128 + cc];
            *(float4*)&Bs[k][c4 * 4] = v;
        }
        __syncthreads();
#pragma unroll
        for (int k = 0; k < BK; ++k) {
            float4 av = *(const float4*)&As[k][rg * 4];
            float a[4] = {av.x, av.y, av.z, av.w};
            float bv[8];
#pragma unroll
            for (int j4 = 0; j4 < 2; ++j4) {
                float4 b = *(const float4*)&Bs[k][cb + j4 * 4];
                bv[j4 * 4 + 0] = b.x; bv[j4 * 4 + 1] = b.y;
                bv[j4 * 4 + 2] = b.z; bv[j4 * 4 + 3] = b.w;
            }
#pragma unroll
            for (int i = 0; i < 4; ++i)
#pragma unroll
                for (int j = 0; j < 8; ++j)
                    acc[i][j] = fmaf(a[i], bv[j], acc[i][j]);
        }
        __syncthreads();
    }
    float* dst = (cb < 128) ? out0 : out1;
    const int cc = cb & 127;
#pragma unroll
    for (int i = 0; i < 4; ++i) {
        int r = m0 + rg * 4 + i;
        if (r < M) {
#pragma unroll
            for (int j4 = 0; j4 < 2; ++j4) {
                float4 v = make_float4(acc[i][j4 * 4 + 0], acc[i][j4 * 4 + 1],
                                       acc[i][j4 * 4 + 2], acc[i][j4 * 4 + 3]);
                *(float4*)&dst[(size_t)r * 128 + cc + j4 * 4] = v;
            }
        }
    }
}

// ------------------------- fused Wo1 + lrelu + Wo2 -------------------------
// out[r,0:2] = lrelu(A[r,:]@W + bias, 0.01) @ W2 + b2.  K=NC=128.
__launch_bounds__(256)
__global__ void gemm_out_k(const float* __restrict__ A, int M,
                           const float* __restrict__ W,
                           const float* __restrict__ bias,
                           const float* __restrict__ W2,
                           const float* __restrict__ b2,
                           float* __restrict__ out)
{
    constexpr int BM = 64, BK = 32;
    __shared__ __align__(16) float As[BK][BM + 4];
    __shared__ __align__(16) float Bs[BK][128];
    __shared__ float red[16][64][2];

    const int t    = threadIdx.x;
    const int m0   = blockIdx.x * BM;
    const int rg   = t & 15;
    const int cgrp = t >> 4;
    const int cb   = cgrp * 8;

    float acc[4][8];
#pragma unroll
    for (int i = 0; i < 4; ++i)
#pragma unroll
        for (int j = 0; j < 8; ++j) acc[i][j] = 0.f;

    for (int kt = 0; kt < 4; ++kt) {
        const int k0 = kt * BK;
#pragma unroll
        for (int i = 0; i < 2; ++i) {
            int idx = t + i * 256;
            int r = idx >> 3, kq = (idx & 7) << 2;
            int gr = m0 + r;
            float4 v = make_float4(0.f, 0.f, 0.f, 0.f);
            if (gr < M) v = *(const float4*)&A[(size_t)gr * 128 + k0 + kq];
            As[kq + 0][r] = v.x; As[kq + 1][r] = v.y;
            As[kq + 2][r] = v.z; As[kq + 3][r] = v.w;
        }
#pragma unroll
        for (int i = 0; i < 4; ++i) {
            int idx = t + i * 256;
            int k = idx >> 5, c4 = (idx & 31) * 4;
            float4 v = *(const float4*)&W[(size_t)(k0 + k) * 128 + c4];
            *(float4*)&Bs[k][c4] = v;
        }
        __syncthreads();
#pragma unroll
        for (int k = 0; k < BK; ++k) {
            float4 av = *(const float4*)&As[k][rg * 4];
            float a[4] = {av.x, av.y, av.z, av.w};
            float bv[8];
#pragma unroll
            for (int j4 = 0; j4 < 2; ++j4) {
                float4 b = *(const float4*)&Bs[k][cb + j4 * 4];
                bv[j4 * 4 + 0] = b.x; bv[j4 * 4 + 1] = b.y;
                bv[j4 * 4 + 2] = b.z; bv[j4 * 4 + 3] = b.w;
            }
#pragma unroll
            for (int i = 0; i < 4; ++i)
#pragma unroll
                for (int j = 0; j < 8; ++j)
                    acc[i][j] = fmaf(a[i], bv[j], acc[i][j]);
        }
        __syncthreads();
    }
    // epilogue: lrelu + project to 2 cols, partial per thread, LDS reduce
    float w2c[8][2], bj[8];
#pragma unroll
    for (int j = 0; j < 8; ++j) {
        w2c[j][0] = W2[(cb + j) * 2 + 0];
        w2c[j][1] = W2[(cb + j) * 2 + 1];
        bj[j]     = bias[cb + j];
    }
#pragma unroll
    for (int i = 0; i < 4; ++i) {
        float p0 = 0.f, p1 = 0.f;
#pragma unroll
        for (int j = 0; j < 8; ++j) {
            float v = acc[i][j] + bj[j];
            v = (v >= 0.f) ? v : 0.01f * v;
            p0 = fmaf(v, w2c[j][0], p0);
            p1 = fmaf(v, w2c[j][1], p1);
        }
        red[cgrp][rg * 4 + i][0] = p0;
        red[cgrp][rg * 4 + i][1] = p1;
    }
    __syncthreads();
    if (t < 128) {
        int row = t >> 1, k = t & 1;
        float s = 0.f;
#pragma unroll
        for (int g = 0; g < 16; ++g) s += red[g][row][k];
        int r = m0 + row;
        if (r < M) out[(size_t)r * 2 + k] = s + b2[k];
    }
}

// ------------------------------ CSR build ----------------------------------
__global__ void count_kernel(const int* __restrict__ dst, int* __restrict__ cnt, int E)
{
    int e = blockIdx.x * 256 + threadIdx.x;
    if (e < E) atomicAdd(&cnt[dst[e]], 1);
}

// single block, 1024 threads: exclusive scan of cnt[0..n) -> off[0..n];
// also resets cnt[i] = off[i] (fill cursor).
__global__ void scan_kernel(int* __restrict__ cnt, int* __restrict__ off, int n)
{
    __shared__ int sums[1024];
    int t = threadIdx.x;
    int per = (n + 1023) >> 10;
    int lo = t * per;
    int hi = lo + per; if (hi > n) hi = n;
    int s = 0;
    for (int i = lo; i < hi; ++i) s += cnt[i];
    sums[t] = s;
    __syncthreads();
    for (int o = 1; o < 1024; o <<= 1) {
        int v = (t >= o) ? sums[t - o] : 0;
        __syncthreads();
        sums[t] += v;
        __syncthreads();
    }
    int base = (t == 0) ? 0 : sums[t - 1];
    for (int i = lo; i < hi; ++i) {
        int d = cnt[i];
        off[i] = base;
        cnt[i] = base;
        base += d;
    }
    if (t == 1023) off[n] = base;
}

// eix[slot] = et*N + src : single packed gather index (xw row / kj row).
__global__ void fill_kernel(const int* __restrict__ src, const int* __restrict__ dst,
                            const int* __restrict__ et, int* __restrict__ cur,
                            int* __restrict__ eix, int N, int E)
{
    int e = blockIdx.x * 256 + threadIdx.x;
    if (e < E) {
        int d = dst[e];
        int slot = atomicAdd(&cur[d], 1);
        eix[slot] = et[e] * N + src[e];
    }
}

// ------------------------- per-node q/k scalars -----------------------------
// qi[r,n,h] = xw[r,n,:] . q[:,h] ; kj likewise with k. One wave per (r,n) row.
template<int H>
__launch_bounds__(256)
__global__ void qk_kernel(const float* __restrict__ xw, const float* __restrict__ q,
                          const float* __restrict__ k, float* __restrict__ qi,
                          float* __restrict__ kj, int N)
{
    int w = blockIdx.x * 4 + (threadIdx.x >> 6);
    if (w >= 2 * N) return;
    int l = threadIdx.x & 63;
    const float* row = xw + (size_t)w * 128;
    float x0 = row[l], x1 = row[l + 64];
    float pq[H], pk[H];
#pragma unroll
    for (int h = 0; h < H; ++h) {
        pq[h] = x0 * q[l * H + h] + x1 * q[(l + 64) * H + h];
        pk[h] = x0 * k[l * H + h] + x1 * k[(l + 64) * H + h];
    }
#pragma unroll
    for (int m = 1; m < 64; m <<= 1) {
#pragma unroll
        for (int h = 0; h < H; ++h) {
            pq[h] += __shfl_xor(pq[h], m);
            pk[h] += __shfl_xor(pk[h], m);
        }
    }
    if (l == 0) {
#pragma unroll
        for (int h = 0; h < H; ++h) {
            qi[(size_t)w * H + h] = pq[h];
            kj[(size_t)w * H + h] = pk[h];
        }
    }
}

// ----------------------- per-node softmax + aggregate -----------------------
// One wave per destination node. H*C == 128. Lane l owns channels l and l+64.
// Fast path (d<=64): lane i owns edge i; alpha/max/sum/weights in registers,
// PV weights broadcast by __shfl. No register array is runtime-indexed.
template<int H, int C>
__launch_bounds__(256)
__global__ void rgat_node_kernel(const float* __restrict__ xw,
                                 const float* __restrict__ qi,
                                 const float* __restrict__ kj,
                                 const int* __restrict__ off,
                                 const int* __restrict__ eix,
                                 const float* __restrict__ bias,
                                 float* __restrict__ out, int N)
{
    int n = blockIdx.x * 4 + (threadIdx.x >> 6);
    if (n >= N) return;
    const int l = threadIdx.x & 63;
    const int start = off[n];
    const int d = off[n + 1] - start;
    const int c0 = l, c1 = l + 64;
    const float b0 = bias[c0], b1 = bias[c1];
    if (d == 0) {
        out[(size_t)n * 128 + c0] = b0;
        out[(size_t)n * 128 + c1] = b1;
        return;
    }
    // qi for this node, both relations (compile-time indexed only)
    float q0[H], q1[H];
#pragma unroll
    for (int h = 0; h < H; ++h) {
        q0[h] = qi[(size_t)n * H + h];
        q1[h] = qi[((size_t)N + n) * H + h];
    }
    const int h0 = c0 / C, h1 = c1 / C;

    float acc0 = 0.f, acc1 = 0.f;
    if (d <= 64) {
        const bool has = (l < d);
        int ridx = 0;
        float a[H];
        if (has) {
            ridx = eix[start + l];
            const bool r1 = (ridx >= N);
            if constexpr (H == 4) {
                float4 kv = *(const float4*)&kj[(size_t)ridx * 4];
                float kk[4] = {kv.x, kv.y, kv.z, kv.w};
#pragma unroll
                for (int h = 0; h < 4; ++h) {
                    float av = (r1 ? q1[h] : q0[h]) + kk[h];
                    a[h] = (av >= 0.f) ? av : 0.2f * av;
                }
            } else {
                float kv = kj[ridx];
                float av = (r1 ? q1[0] : q0[0]) + kv;
                a[0] = (av >= 0.f) ? av : 0.2f * av;
            }
        } else {
#pragma unroll
            for (int h = 0; h < H; ++h) a[h] = -INFINITY;
        }
        float mx[H], ex[H], sm[H], wgt[H];
#pragma unroll
        for (int h = 0; h < H; ++h) mx[h] = a[h];
#pragma unroll
        for (int m = 1; m < 64; m <<= 1)
#pragma unroll
            for (int h = 0; h < H; ++h) mx[h] = fmaxf(mx[h], __shfl_xor(mx[h], m));
#pragma unroll
        for (int h = 0; h < H; ++h) { ex[h] = has ? __expf(a[h] - mx[h]) : 0.f; sm[h] = ex[h]; }
#pragma unroll
        for (int m = 1; m < 64; m <<= 1)
#pragma unroll
            for (int h = 0; h < H; ++h) sm[h] += __shfl_xor(sm[h], m);
#pragma unroll
        for (int h = 0; h < H; ++h) wgt[h] = ex[h] / (sm[h] + 1e-16f);

        // PV: serial over edges, 2-deep pipelined row gather
        int rB = __shfl(ridx, 0);
        const float* rowB = xw + (size_t)rB * 128;
        float vB0 = rowB[c0], vB1 = rowB[c1];
        for (int i = 0; i < d; ++i) {
            float vN0 = 0.f, vN1 = 0.f;
            if (i + 1 < d) {
                int rN = __shfl(ridx, i + 1);
                const float* rowN = xw + (size_t)rN * 128;
                vN0 = rowN[c0]; vN1 = rowN[c1];
            }
            float w0_, w1_;
            if constexpr (H == 4) {
                float s0 = __shfl(wgt[0], i), s1 = __shfl(wgt[1], i);
                float s2 = __shfl(wgt[2], i), s3 = __shfl(wgt[3], i);
                w0_ = (h0 & 1) ? s1 : s0;   // h0 in {0,1}
                w1_ = (h1 & 1) ? s3 : s2;   // h1 in {2,3}
            } else {
                float s = __shfl(wgt[0], i);
                w0_ = s; w1_ = s;
            }
            acc0 = fmaf(w0_, vB0, acc0);
            acc1 = fmaf(w1_, vB1, acc1);
            vB0 = vN0; vB1 = vN1;
        }
    } else {
        // ---- generic fallback, 3 passes (rare: d > 64) ----
        float mx[H];
#pragma unroll
        for (int h = 0; h < H; ++h) mx[h] = -INFINITY;
        for (int i = l; i < d; i += 64) {
            int ridx = eix[start + i];
            const bool r1 = (ridx >= N);
            if constexpr (H == 4) {
                float4 kv = *(const float4*)&kj[(size_t)ridx * 4];
                float kk[4] = {kv.x, kv.y, kv.z, kv.w};
#pragma unroll
                for (int h = 0; h < 4; ++h) {
                    float av = (r1 ? q1[h] : q0[h]) + kk[h];
                    av = (av >= 0.f) ? av : 0.2f * av;
                    mx[h] = fmaxf(mx[h], av);
                }
            } else {
                float kv = kj[ridx];
                float av = (r1 ? q1[0] : q0[0]) + kv;
                av = (av >= 0.f) ? av : 0.2f * av;
                mx[0] = fmaxf(mx[0], av);
            }
        }
#pragma unroll
        for (int m = 1; m < 64; m <<= 1)
#pragma unroll
            for (int h = 0; h < H; ++h) mx[h] = fmaxf(mx[h], __shfl_xor(mx[h], m));
        float sm[H];
#pragma unroll
        for (int h = 0; h < H; ++h) sm[h] = 0.f;
        for (int i = l; i < d; i += 64) {
            int ridx = eix[start + i];
            const bool r1 = (ridx >= N);
            if constexpr (H == 4) {
                float4 kv = *(const float4*)&kj[(size_t)ridx * 4];
                float kk[4] = {kv.x, kv.y, kv.z, kv.w};
#pragma unroll
                for (int h = 0; h < 4; ++h) {
                    float av = (r1 ? q1[h] : q0[h]) + kk[h];
                    av = (av >= 0.f) ? av : 0.2f * av;
                    sm[h] += __expf(av - mx[h]);
                }
            } else {
                float kv = kj[ridx];
                float av = (r1 ? q1[0] : q0[0]) + kv;
                av = (av >= 0.f) ? av : 0.2f * av;
                sm[0] += __expf(av - mx[0]);
            }
        }
#pragma unroll
        for (int m = 1; m < 64; m <<= 1)
#pragma unroll
            for (int h = 0; h < H; ++h) sm[h] += __shfl_xor(sm[h], m);
        float rden[H];
#pragma unroll
        for (int h = 0; h < H; ++h) rden[h] = 1.f / (sm[h] + 1e-16f);

        // per-lane head-selected scalars (no runtime register-array indexing)
        float q0h0, q1h0, q0h1, q1h1, mxh0, mxh1, rdh0, rdh1;
        if constexpr (H == 4) {
            q0h0 = (h0 & 1) ? q0[1] : q0[0];  q1h0 = (h0 & 1) ? q1[1] : q1[0];
            q0h1 = (h1 & 1) ? q0[3] : q0[2];  q1h1 = (h1 & 1) ? q1[3] : q1[2];
            mxh0 = (h0 & 1) ? mx[1] : mx[0];  mxh1 = (h1 & 1) ? mx[3] : mx[2];
            rdh0 = (h0 & 1) ? rden[1] : rden[0];
            rdh1 = (h1 & 1) ? rden[3] : rden[2];
        } else {
            q0h0 = q0[0]; q1h0 = q1[0]; q0h1 = q0[0]; q1h1 = q1[0];
            mxh0 = mx[0]; mxh1 = mx[0]; rdh0 = rden[0]; rdh1 = rden[0];
        }
        for (int i = 0; i < d; ++i) {
            int ridx = eix[start + i];          // wave-uniform broadcast
            const bool r1 = (ridx >= N);
            float kh0, kh1;
            if constexpr (H == 4) {
                float4 kv = *(const float4*)&kj[(size_t)ridx * 4];
                kh0 = (h0 & 1) ? kv.y : kv.x;
                kh1 = (h1 & 1) ? kv.w : kv.z;
            } else {
                float kv = kj[ridx];
                kh0 = kv; kh1 = kv;
            }
            float a0 = (r1 ? q1h0 : q0h0) + kh0;
            a0 = (a0 >= 0.f) ? a0 : 0.2f * a0;
            float a1 = (r1 ? q1h1 : q0h1) + kh1;
            a1 = (a1 >= 0.f) ? a1 : 0.2f * a1;
            float w0 = __expf(a0 - mxh0) * rdh0;
            float w1 = __expf(a1 - mxh1) * rdh1;
            const float* row = xw + (size_t)ridx * 128;
            acc0 = fmaf(w0, row[c0], acc0);
            acc1 = fmaf(w1, row[c1], acc1);
        }
    }
    out[(size_t)n * 128 + c0] = acc0 + b0;
    out[(size_t)n * 128 + c1] = acc1 + b1;
}

// ---------------------------------------------------------------------------
extern "C" void kernel_launch(void* const* d_in, const int* in_sizes, int n_in,
                              void* d_out, int out_size, void* d_ws, size_t ws_size,
                              hipStream_t stream)
{
    const float* des   = (const float*)d_in[0];
    const float* tweet = (const float*)d_in[1];
    const float* nump  = (const float*)d_in[2];
    const float* catp  = (const float*)d_in[3];
    const float* newf  = (const float*)d_in[4];
    const int*   eidx  = (const int*)d_in[5];
    const int*   etype = (const int*)d_in[6];
    const float* Wd = (const float*)d_in[7],  *bd = (const float*)d_in[8];
    const float* Wt = (const float*)d_in[9],  *bt = (const float*)d_in[10];
    const float* Wn = (const float*)d_in[11], *bn = (const float*)d_in[12];
    const float* Wc = (const float*)d_in[13], *bc = (const float*)d_in[14];
    const float* Wf = (const float*)d_in[15], *bf = (const float*)d_in[16];
    const float* Wi = (const float*)d_in[17], *bi = (const float*)d_in[18];
    const float* w1 = (const float*)d_in[19], *q1 = (const float*)d_in[20];
    const float* k1 = (const float*)d_in[21], *b1 = (const float*)d_in[22];
    const float* w2 = (const float*)d_in[23], *q2 = (const float*)d_in[24];
    const float* k2 = (const float*)d_in[25], *b2 = (const float*)d_in[26];
    const float* Wo1 = (const float*)d_in[27], *bo1 = (const float*)d_in[28];
    const float* Wo2 = (const float*)d_in[29], *bo2 = (const float*)d_in[30];

    const int N = in_sizes[4];   // new_feature is [N,1]
    const int E = in_sizes[6];   // edge_type is [E]
    const int* esrc = eidx;      // edge_index[0]
    const int* edst = eidx + E;  // edge_index[1]

    // workspace carve-out (all 256B-aligned); ~109 MB total
    char* wsp = (char*)d_ws;
    size_t o = 0;
    auto alloc = [&](size_t bytes) -> char* {
        char* p = wsp + o;
        o = (o + bytes + 255) & ~(size_t)255;
        return p;
    };
    float* xA   = (float*)alloc((size_t)N * 128 * 4);
    float* xB   = (float*)alloc((size_t)N * 128 * 4);
    float* xw   = (float*)alloc((size_t)2 * N * 128 * 4);
    float* qi   = (float*)alloc((size_t)2 * N * 4 * 4);
    float* kj   = (float*)alloc((size_t)2 * N * 4 * 4);
    int*   off  = (int*)alloc((size_t)(N + 1) * 4);
    int*   cur  = (int*)alloc((size_t)N * 4);
    int*   eix  = (int*)alloc((size_t)E * 4);

    const int gM  = (N + 63) / 64;
    const int gE  = (E + 255) / 256;
    const int gN4 = (N + 3) / 4;
    const int gW2 = (2 * N + 3) / 4;

    // 1) feature linears -> xA (columns 0,28,64,76,116)
    gemm_lrelu_k<28, 4><<<gM, 256, 0, stream>>>(des,   768, N, Wd, bd, xA, 128, 0);
    gemm_lrelu_k<36, 4><<<gM, 256, 0, stream>>>(tweet, 768, N, Wt, bt, xA, 128, 28);
    gemm_lrelu_k<12, 4><<<gM, 256, 0, stream>>>(nump,  7,   N, Wn, bn, xA, 128, 64);
    gemm_lrelu_k<40, 4><<<gM, 256, 0, stream>>>(catp,  11,  N, Wc, bc, xA, 128, 76);
    gemm_lrelu_k<12, 4><<<gM, 256, 0, stream>>>(newf,  1,   N, Wf, bf, xA, 128, 116);
    // 2) input linear -> xB
    gemm_lrelu_k<128, 8><<<gM, 256, 0, stream>>>(xA, 128, N, Wi, bi, xB, 128, 0);

    // 3) CSR (dst-sorted packed edge indices); rebuilt every call
    hipMemsetAsync(cur, 0, (size_t)N * 4, stream);
    count_kernel<<<gE, 256, 0, stream>>>(edst, cur, E);
    scan_kernel<<<1, 1024, 0, stream>>>(cur, off, N);
    fill_kernel<<<gE, 256, 0, stream>>>(esrc, edst, etype, cur, eix, N, E);

    // 4) RGAT layer 1 (H=4, C=32): xB -> xA
    gemm_dual_k<<<gM, 512, 0, stream>>>(xB, N, w1, w1 + 16384, xw, xw + (size_t)N * 128);
    qk_kernel<4><<<gW2, 256, 0, stream>>>(xw, q1, k1, qi, kj, N);
    rgat_node_kernel<4, 32><<<gN4, 256, 0, stream>>>(xw, qi, kj, off, eix, b1, xA, N);

    // 5) RGAT layer 2 (H=1, C=128): xA -> xB
    gemm_dual_k<<<gM, 512, 0, stream>>>(xA, N, w2, w2 + 16384, xw, xw + (size_t)N * 128);
    qk_kernel<1><<<gW2, 256, 0, stream>>>(xw, q2, k2, qi, kj, N);
    rgat_node_kernel<1, 128><<<gN4, 256, 0, stream>>>(xw, qi, kj, off, eix, b2, xB, N);

    // 6) fused output linears -> d_out [N,2]
    gemm_out_k<<<gM, 256, 0, stream>>>(xB, N, Wo1, bo1, Wo2, bo2, (float*)d_out);
}

// Round 8
// 964.194 us; speedup vs baseline: 9.6950x; 1.0877x over previous
//
#include <hip/hip_runtime.h>
#include <math.h>

// ---------------------------------------------------------------------------
// ESABot RGAT pipeline, fp32 throughout.
//   1) feat = concat(lrelu(des@Wd+bd), ..., lrelu(newf@Wf+bf))   [N,128]
//   2) x1 = lrelu(feat@Wi+bi)                                    [N,128]
//   3) CSR build (dst-sorted edge list, packed ridx = et*N+src)
//   4) RGAT layer: dual-relation GEMM xw[r]=x@w[r]; qi/kj per-node scalars;
//      per-node wave softmax + gather-aggregate (+bias)
//   5) repeat RGAT (H=1); fused lrelu(x@Wo1+bo1)@Wo2+bo2 -> out [N,2]
//
// R2 lesson: acc[4][16] + kt-unroll in the dual GEMM spilled (VGPR=256 cap,
// 6.5 GB scratch traffic). Dual GEMM now 512 thr / acc[4][8].
// R3 lesson: single-block scan_kernel was 109 us (Occupancy 0.14% -- one CU,
// latency-bound serial loop). Now a 3-phase parallel scan (~10 us total).
// R4: PV gather loop batched in groups of 4 (4 outstanding L3 gathers/wave).
// R6: count buffer scanned in place (cur doubles as cnt).
// R7: resubmit unchanged (4th consecutive infra failure; deltas unmeasured).
// ---------------------------------------------------------------------------

// ------------------------------ generic GEMM -------------------------------
// out[r, col_off+c] = lrelu( sum_k A[r,k]*W[k,c] + bias[c], 0.01 )
// BM=64 rows/block, BK=32, 256 threads. Thread (rg,cgrp): rows rg*4..+3,
// cols cgrp*RN..+RN-1. As staged transposed [BK][BM+4] so a 4-row fragment
// is one aligned ds_read_b128. A staging float4-vectorized when K%4==0.
template<int NC, int RN>
__launch_bounds__(256)
__global__ void gemm_lrelu_k(const float* __restrict__ A, int K, int M,
                             const float* __restrict__ W,
                             const float* __restrict__ bias,
                             float* __restrict__ out, int ldo, int col_off)
{
    constexpr int BM = 64, BK = 32;
    __shared__ __align__(16) float As[BK][BM + 4];
    __shared__ __align__(16) float Bs[BK][NC];

    const int t    = threadIdx.x;
    const int m0   = blockIdx.x * BM;
    const int rg   = t & 15;
    const int cgrp = t >> 4;
    const int cb   = cgrp * RN;
    const bool act = (cb < NC);
    const bool vec = ((K & 3) == 0);

    float acc[4][RN];
#pragma unroll
    for (int i = 0; i < 4; ++i)
#pragma unroll
        for (int j = 0; j < RN; ++j) acc[i][j] = 0.f;

    const int nk = (K + BK - 1) / BK;
    for (int kt = 0; kt < nk; ++kt) {
        const int k0 = kt * BK;
        if (vec) {
            // 64x32 tile = 512 float4; 2 per thread
#pragma unroll
            for (int i = 0; i < 2; ++i) {
                int idx = t + i * 256;
                int r = idx >> 3, kq = (idx & 7) << 2;
                int gr = m0 + r, gk = k0 + kq;
                float4 v = make_float4(0.f, 0.f, 0.f, 0.f);
                if (gr < M && gk < K) v = *(const float4*)&A[(size_t)gr * K + gk];
                As[kq + 0][r] = v.x; As[kq + 1][r] = v.y;
                As[kq + 2][r] = v.z; As[kq + 3][r] = v.w;
            }
        } else {
#pragma unroll
            for (int i = 0; i < 8; ++i) {
                int idx = t + i * 256;
                int r = idx >> 5, kk = idx & 31;
                int gr = m0 + r, gk = k0 + kk;
                float v = 0.f;
                if (gr < M && gk < K) v = A[(size_t)gr * K + gk];
                As[kk][r] = v;
            }
        }
        constexpr int NB4 = BK * NC / 4;
        for (int idx = t; idx < NB4; idx += 256) {
            int k = idx / (NC / 4), c4 = (idx % (NC / 4)) * 4;
            int gk = k0 + k;
            float4 v = make_float4(0.f, 0.f, 0.f, 0.f);
            if (gk < K) v = *(const float4*)&W[(size_t)gk * NC + c4];
            *(float4*)&Bs[k][c4] = v;
        }
        __syncthreads();
        if (act) {
#pragma unroll
            for (int k = 0; k < BK; ++k) {
                float4 av = *(const float4*)&As[k][rg * 4];
                float a[4] = {av.x, av.y, av.z, av.w};
                float bv[RN];
#pragma unroll
                for (int j4 = 0; j4 < RN / 4; ++j4) {
                    float4 b = *(const float4*)&Bs[k][cb + j4 * 4];
                    bv[j4 * 4 + 0] = b.x; bv[j4 * 4 + 1] = b.y;
                    bv[j4 * 4 + 2] = b.z; bv[j4 * 4 + 3] = b.w;
                }
#pragma unroll
                for (int i = 0; i < 4; ++i)
#pragma unroll
                    for (int j = 0; j < RN; ++j)
                        acc[i][j] = fmaf(a[i], bv[j], acc[i][j]);
            }
        }
        __syncthreads();
    }
    if (act) {
        float bj[RN];
#pragma unroll
        for (int j = 0; j < RN; ++j) bj[j] = bias[cb + j];
#pragma unroll
        for (int i = 0; i < 4; ++i) {
            int r = m0 + rg * 4 + i;
            if (r < M) {
#pragma unroll
                for (int j4 = 0; j4 < RN / 4; ++j4) {
                    float4 v;
                    float o0 = acc[i][j4 * 4 + 0] + bj[j4 * 4 + 0];
                    float o1 = acc[i][j4 * 4 + 1] + bj[j4 * 4 + 1];
                    float o2 = acc[i][j4 * 4 + 2] + bj[j4 * 4 + 2];
                    float o3 = acc[i][j4 * 4 + 3] + bj[j4 * 4 + 3];
                    v.x = (o0 >= 0.f) ? o0 : 0.01f * o0;
                    v.y = (o1 >= 0.f) ? o1 : 0.01f * o1;
                    v.z = (o2 >= 0.f) ? o2 : 0.01f * o2;
                    v.w = (o3 >= 0.f) ? o3 : 0.01f * o3;
                    *(float4*)&out[(size_t)r * ldo + col_off + cb + j4 * 4] = v;
                }
            }
        }
    }
}

// --------------------------- dual-relation GEMM ----------------------------
// xw[r] = A @ W_r for r=0,1 in one pass (A tile staged once, reused for both
// relation weight matrices). K = NC = 128 fixed. No bias, no activation.
// 512 threads, per-thread tile 4x8 (acc = 32 VGPR) -- R2's 4x16 spilled.
__launch_bounds__(512)
__global__ void gemm_dual_k(const float* __restrict__ A, int M,
                            const float* __restrict__ W0,
                            const float* __restrict__ W1,
                            float* __restrict__ out0,
                            float* __restrict__ out1)
{
    constexpr int BM = 64, BK = 32;
    __shared__ __align__(16) float As[BK][BM + 4];
    __shared__ __align__(16) float Bs[BK][256];

    const int t    = threadIdx.x;
    const int m0   = blockIdx.x * BM;
    const int rg   = t & 15;        // 16 row-groups of 4 rows
    const int cgrp = t >> 4;        // 0..31
    const int cb   = cgrp * 8;      // 32 groups x 8 cols = 256

    float acc[4][8];
#pragma unroll
    for (int i = 0; i < 4; ++i)
#pragma unroll
        for (int j = 0; j < 8; ++j) acc[i][j] = 0.f;

    for (int kt = 0; kt < 4; ++kt) {
        const int k0 = kt * BK;
        // A tile 64x32 transposed: 512 float4, 1 per thread
        {
            int r = t >> 3, kq = (t & 7) << 2;
            int gr = m0 + r;
            float4 v = make_float4(0.f, 0.f, 0.f, 0.f);
            if (gr < M) v = *(const float4*)&A[(size_t)gr * 128 + k0 + kq];
            As[kq + 0][r] = v.x; As[kq + 1][r] = v.y;
            As[kq + 2][r] = v.z; As[kq + 3][r] = v.w;
        }
        // B tile 32x256 (both relations): 2048 float4, 4 per thread
#pragma unroll
        for (int i = 0; i < 4; ++i) {
            int idx = t + i * 512;
            int k = idx >> 6, c4 = idx & 63;
            const float* Wp = (c4 < 32) ? W0 : W1;
            int cc = (c4 & 31) * 4;
            float4 v = *(const float4*)&Wp[(size_t)(k0 + k) * 128 + cc];
            *(float4*)&Bs[k][c4 * 4] = v;
        }
        __syncthreads();
#pragma unroll
        for (int k = 0; k < BK; ++k) {
            float4 av = *(const float4*)&As[k][rg * 4];
            float a[4] = {av.x, av.y, av.z, av.w};
            float bv[8];
#pragma unroll
            for (int j4 = 0; j4 < 2; ++j4) {
                float4 b = *(const float4*)&Bs[k][cb + j4 * 4];
                bv[j4 * 4 + 0] = b.x; bv[j4 * 4 + 1] = b.y;
                bv[j4 * 4 + 2] = b.z; bv[j4 * 4 + 3] = b.w;
            }
#pragma unroll
            for (int i = 0; i < 4; ++i)
#pragma unroll
                for (int j = 0; j < 8; ++j)
                    acc[i][j] = fmaf(a[i], bv[j], acc[i][j]);
        }
        __syncthreads();
    }
    float* dst = (cb < 128) ? out0 : out1;
    const int cc = cb & 127;
#pragma unroll
    for (int i = 0; i < 4; ++i) {
        int r = m0 + rg * 4 + i;
        if (r < M) {
#pragma unroll
            for (int j4 = 0; j4 < 2; ++j4) {
                float4 v = make_float4(acc[i][j4 * 4 + 0], acc[i][j4 * 4 + 1],
                                       acc[i][j4 * 4 + 2], acc[i][j4 * 4 + 3]);
                *(float4*)&dst[(size_t)r * 128 + cc + j4 * 4] = v;
            }
        }
    }
}

// ------------------------- fused Wo1 + lrelu + Wo2 -------------------------
// out[r,0:2] = lrelu(A[r,:]@W + bias, 0.01) @ W2 + b2.  K=NC=128.
__launch_bounds__(256)
__global__ void gemm_out_k(const float* __restrict__ A, int M,
                           const float* __restrict__ W,
                           const float* __restrict__ bias,
                           const float* __restrict__ W2,
                           const float* __restrict__ b2,
                           float* __restrict__ out)
{
    constexpr int BM = 64, BK = 32;
    __shared__ __align__(16) float As[BK][BM + 4];
    __shared__ __align__(16) float Bs[BK][128];
    __shared__ float red[16][64][2];

    const int t    = threadIdx.x;
    const int m0   = blockIdx.x * BM;
    const int rg   = t & 15;
    const int cgrp = t >> 4;
    const int cb   = cgrp * 8;

    float acc[4][8];
#pragma unroll
    for (int i = 0; i < 4; ++i)
#pragma unroll
        for (int j = 0; j < 8; ++j) acc[i][j] = 0.f;

    for (int kt = 0; kt < 4; ++kt) {
        const int k0 = kt * BK;
#pragma unroll
        for (int i = 0; i < 2; ++i) {
            int idx = t + i * 256;
            int r = idx >> 3, kq = (idx & 7) << 2;
            int gr = m0 + r;
            float4 v = make_float4(0.f, 0.f, 0.f, 0.f);
            if (gr < M) v = *(const float4*)&A[(size_t)gr * 128 + k0 + kq];
            As[kq + 0][r] = v.x; As[kq + 1][r] = v.y;
            As[kq + 2][r] = v.z; As[kq + 3][r] = v.w;
        }
#pragma unroll
        for (int i = 0; i < 4; ++i) {
            int idx = t + i * 256;
            int k = idx >> 5, c4 = (idx & 31) * 4;
            float4 v = *(const float4*)&W[(size_t)(k0 + k) * 128 + c4];
            *(float4*)&Bs[k][c4] = v;
        }
        __syncthreads();
#pragma unroll
        for (int k = 0; k < BK; ++k) {
            float4 av = *(const float4*)&As[k][rg * 4];
            float a[4] = {av.x, av.y, av.z, av.w};
            float bv[8];
#pragma unroll
            for (int j4 = 0; j4 < 2; ++j4) {
                float4 b = *(const float4*)&Bs[k][cb + j4 * 4];
                bv[j4 * 4 + 0] = b.x; bv[j4 * 4 + 1] = b.y;
                bv[j4 * 4 + 2] = b.z; bv[j4 * 4 + 3] = b.w;
            }
#pragma unroll
            for (int i = 0; i < 4; ++i)
#pragma unroll
                for (int j = 0; j < 8; ++j)
                    acc[i][j] = fmaf(a[i], bv[j], acc[i][j]);
        }
        __syncthreads();
    }
    // epilogue: lrelu + project to 2 cols, partial per thread, LDS reduce
    float w2c[8][2], bj[8];
#pragma unroll
    for (int j = 0; j < 8; ++j) {
        w2c[j][0] = W2[(cb + j) * 2 + 0];
        w2c[j][1] = W2[(cb + j) * 2 + 1];
        bj[j]     = bias[cb + j];
    }
#pragma unroll
    for (int i = 0; i < 4; ++i) {
        float p0 = 0.f, p1 = 0.f;
#pragma unroll
        for (int j = 0; j < 8; ++j) {
            float v = acc[i][j] + bj[j];
            v = (v >= 0.f) ? v : 0.01f * v;
            p0 = fmaf(v, w2c[j][0], p0);
            p1 = fmaf(v, w2c[j][1], p1);
        }
        red[cgrp][rg * 4 + i][0] = p0;
        red[cgrp][rg * 4 + i][1] = p1;
    }
    __syncthreads();
    if (t < 128) {
        int row = t >> 1, k = t & 1;
        float s = 0.f;
#pragma unroll
        for (int g = 0; g < 16; ++g) s += red[g][row][k];
        int r = m0 + row;
        if (r < M) out[(size_t)r * 2 + k] = s + b2[k];
    }
}

// ------------------------------ CSR build ----------------------------------
__global__ void count_kernel(const int* __restrict__ dst, int* __restrict__ cnt, int E)
{
    int e = blockIdx.x * 256 + threadIdx.x;
    if (e < E) atomicAdd(&cnt[dst[e]], 1);
}

// R3: 3-phase parallel scan replaces the 1-block serial scan (was 109 us).
// Phase B: per-block (2048 counters) sums.
__launch_bounds__(256)
__global__ void scan_bsum_k(const int* __restrict__ cnt, int* __restrict__ bsum, int n)
{
    int base = blockIdx.x * 2048 + threadIdx.x * 8;
    int s = 0;
#pragma unroll
    for (int i = 0; i < 8; ++i) s += (base + i < n) ? cnt[base + i] : 0;
#pragma unroll
    for (int m = 1; m < 64; m <<= 1) s += __shfl_xor(s, m);
    __shared__ int ws_[4];
    if ((threadIdx.x & 63) == 0) ws_[threadIdx.x >> 6] = s;
    __syncthreads();
    if (threadIdx.x == 0) bsum[blockIdx.x] = ws_[0] + ws_[1] + ws_[2] + ws_[3];
}

// Phase C: single block scans block sums (nb <= 256), writes off[N] = total.
__launch_bounds__(256)
__global__ void scan_top_k(const int* __restrict__ bsum, int* __restrict__ bpre,
                           int nb, int* __restrict__ off, int N)
{
    __shared__ int s_[256];
    int t = threadIdx.x;
    int v = (t < nb) ? bsum[t] : 0;
    s_[t] = v;
    __syncthreads();
    for (int o = 1; o < 256; o <<= 1) {
        int u = (t >= o) ? s_[t - o] : 0;
        __syncthreads();
        s_[t] += u;
        __syncthreads();
    }
    if (t < nb) bpre[t] = s_[t] - v;      // exclusive block prefix
    if (t == 255) off[N] = s_[255];       // grand total == E
}

// Phase D: per-block local exclusive scan + block prefix -> off[] and cur[].
// NOTE: cnt and cur may alias (in-place scan): each element is read exactly
// once by the same thread that later writes it, so no __restrict__ here.
__launch_bounds__(256)
__global__ void scan_write_k(const int* cnt, const int* __restrict__ bpre,
                             int* __restrict__ off, int* cur, int n)
{
    int t = threadIdx.x;
    int base = blockIdx.x * 2048 + t * 8;
    int v[8], p[8];
    int s = 0;
#pragma unroll
    for (int i = 0; i < 8; ++i) {
        v[i] = (base + i < n) ? cnt[base + i] : 0;
        p[i] = s;
        s += v[i];
    }
    __shared__ int sums[256];
    sums[t] = s;
    __syncthreads();
    for (int o = 1; o < 256; o <<= 1) {
        int u = (t >= o) ? sums[t - o] : 0;
        __syncthreads();
        sums[t] += u;
        __syncthreads();
    }
    int pref = bpre[blockIdx.x] + (sums[t] - s);
#pragma unroll
    for (int i = 0; i < 8; ++i) {
        int idx = base + i;
        if (idx < n) {
            int o_ = pref + p[i];
            off[idx] = o_;
            cur[idx] = o_;
        }
    }
}

// eix[slot] = et*N + src : single packed gather index (xw row / kj row).
__global__ void fill_kernel(const int* __restrict__ src, const int* __restrict__ dst,
                            const int* __restrict__ et, int* __restrict__ cur,
                            int* __restrict__ eix, int N, int E)
{
    int e = blockIdx.x * 256 + threadIdx.x;
    if (e < E) {
        int d = dst[e];
        int slot = atomicAdd(&cur[d], 1);
        eix[slot] = et[e] * N + src[e];
    }
}

// ------------------------- per-node q/k scalars -----------------------------
// qi[r,n,h] = xw[r,n,:] . q[:,h] ; kj likewise with k. One wave per (r,n) row.
template<int H>
__launch_bounds__(256)
__global__ void qk_kernel(const float* __restrict__ xw, const float* __restrict__ q,
                          const float* __restrict__ k, float* __restrict__ qi,
                          float* __restrict__ kj, int N)
{
    int w = blockIdx.x * 4 + (threadIdx.x >> 6);
    if (w >= 2 * N) return;
    int l = threadIdx.x & 63;
    const float* row = xw + (size_t)w * 128;
    float x0 = row[l], x1 = row[l + 64];
    float pq[H], pk[H];
#pragma unroll
    for (int h = 0; h < H; ++h) {
        pq[h] = x0 * q[l * H + h] + x1 * q[(l + 64) * H + h];
        pk[h] = x0 * k[l * H + h] + x1 * k[(l + 64) * H + h];
    }
#pragma unroll
    for (int m = 1; m < 64; m <<= 1) {
#pragma unroll
        for (int h = 0; h < H; ++h) {
            pq[h] += __shfl_xor(pq[h], m);
            pk[h] += __shfl_xor(pk[h], m);
        }
    }
    if (l == 0) {
#pragma unroll
        for (int h = 0; h < H; ++h) {
            qi[(size_t)w * H + h] = pq[h];
            kj[(size_t)w * H + h] = pk[h];
        }
    }
}

// ----------------------- per-node softmax + aggregate -----------------------
// One wave per destination node. H*C == 128. Lane l owns channels l and l+64.
// Fast path (d<=64): lane i owns edge i; alpha/max/sum/weights in registers,
// PV weights broadcast by __shfl. No register array is runtime-indexed.
// R4: PV loop processes 4 edges/group -> 4 outstanding row gathers (MLP).
template<int H, int C>
__launch_bounds__(256)
__global__ void rgat_node_kernel(const float* __restrict__ xw,
                                 const float* __restrict__ qi,
                                 const float* __restrict__ kj,
                                 const int* __restrict__ off,
                                 const int* __restrict__ eix,
                                 const float* __restrict__ bias,
                                 float* __restrict__ out, int N)
{
    int n = blockIdx.x * 4 + (threadIdx.x >> 6);
    if (n >= N) return;
    const int l = threadIdx.x & 63;
    const int start = off[n];
    const int d = off[n + 1] - start;
    const int c0 = l, c1 = l + 64;
    const float b0 = bias[c0], b1 = bias[c1];
    if (d == 0) {
        out[(size_t)n * 128 + c0] = b0;
        out[(size_t)n * 128 + c1] = b1;
        return;
    }
    // qi for this node, both relations (compile-time indexed only)
    float q0[H], q1[H];
#pragma unroll
    for (int h = 0; h < H; ++h) {
        q0[h] = qi[(size_t)n * H + h];
        q1[h] = qi[((size_t)N + n) * H + h];
    }
    const int h0 = c0 / C, h1 = c1 / C;

    float acc0 = 0.f, acc1 = 0.f;
    if (d <= 64) {
        const bool has = (l < d);
        int ridx = 0;
        float a[H];
        if (has) {
            ridx = eix[start + l];
            const bool r1 = (ridx >= N);
            if constexpr (H == 4) {
                float4 kv = *(const float4*)&kj[(size_t)ridx * 4];
                float kk[4] = {kv.x, kv.y, kv.z, kv.w};
#pragma unroll
                for (int h = 0; h < 4; ++h) {
                    float av = (r1 ? q1[h] : q0[h]) + kk[h];
                    a[h] = (av >= 0.f) ? av : 0.2f * av;
                }
            } else {
                float kv = kj[ridx];
                float av = (r1 ? q1[0] : q0[0]) + kv;
                a[0] = (av >= 0.f) ? av : 0.2f * av;
            }
        } else {
#pragma unroll
            for (int h = 0; h < H; ++h) a[h] = -INFINITY;
        }
        float mx[H], ex[H], sm[H], wgt[H];
#pragma unroll
        for (int h = 0; h < H; ++h) mx[h] = a[h];
#pragma unroll
        for (int m = 1; m < 64; m <<= 1)
#pragma unroll
            for (int h = 0; h < H; ++h) mx[h] = fmaxf(mx[h], __shfl_xor(mx[h], m));
#pragma unroll
        for (int h = 0; h < H; ++h) { ex[h] = has ? __expf(a[h] - mx[h]) : 0.f; sm[h] = ex[h]; }
#pragma unroll
        for (int m = 1; m < 64; m <<= 1)
#pragma unroll
            for (int h = 0; h < H; ++h) sm[h] += __shfl_xor(sm[h], m);
#pragma unroll
        for (int h = 0; h < H; ++h) wgt[h] = ex[h] / (sm[h] + 1e-16f);

        // PV: groups of 4 edges; 4 independent row gathers in flight.
        for (int i0 = 0; i0 < d; i0 += 4) {
            const int j1 = (i0 + 1 < d) ? i0 + 1 : i0;
            const int j2 = (i0 + 2 < d) ? i0 + 2 : i0;
            const int j3 = (i0 + 3 < d) ? i0 + 3 : i0;
            int r0 = __shfl(ridx, i0), r1_ = __shfl(ridx, j1);
            int r2 = __shfl(ridx, j2), r3 = __shfl(ridx, j3);
            float va0, va1, vb0 = 0.f, vb1 = 0.f;
            float vc0 = 0.f, vc1 = 0.f, vd0 = 0.f, vd1 = 0.f;
            { const float* rp = xw + (size_t)r0 * 128; va0 = rp[c0]; va1 = rp[c1]; }
            if (i0 + 1 < d) { const float* rp = xw + (size_t)r1_ * 128; vb0 = rp[c0]; vb1 = rp[c1]; }
            if (i0 + 2 < d) { const float* rp = xw + (size_t)r2 * 128; vc0 = rp[c0]; vc1 = rp[c1]; }
            if (i0 + 3 < d) { const float* rp = xw + (size_t)r3 * 128; vd0 = rp[c0]; vd1 = rp[c1]; }
            float wa0, wa1, wb0, wb1, wc0, wc1, wd0, wd1;
            if constexpr (H == 4) {
                float u0, u1, u2, u3;
                u0 = __shfl(wgt[0], i0); u1 = __shfl(wgt[1], i0);
                u2 = __shfl(wgt[2], i0); u3 = __shfl(wgt[3], i0);
                wa0 = (h0 & 1) ? u1 : u0;  wa1 = (h1 & 1) ? u3 : u2;
                u0 = __shfl(wgt[0], j1); u1 = __shfl(wgt[1], j1);
                u2 = __shfl(wgt[2], j1); u3 = __shfl(wgt[3], j1);
                wb0 = (h0 & 1) ? u1 : u0;  wb1 = (h1 & 1) ? u3 : u2;
                u0 = __shfl(wgt[0], j2); u1 = __shfl(wgt[1], j2);
                u2 = __shfl(wgt[2], j2); u3 = __shfl(wgt[3], j2);
                wc0 = (h0 & 1) ? u1 : u0;  wc1 = (h1 & 1) ? u3 : u2;
                u0 = __shfl(wgt[0], j3); u1 = __shfl(wgt[1], j3);
                u2 = __shfl(wgt[2], j3); u3 = __shfl(wgt[3], j3);
                wd0 = (h0 & 1) ? u1 : u0;  wd1 = (h1 & 1) ? u3 : u2;
            } else {
                float s;
                s = __shfl(wgt[0], i0); wa0 = s; wa1 = s;
                s = __shfl(wgt[0], j1); wb0 = s; wb1 = s;
                s = __shfl(wgt[0], j2); wc0 = s; wc1 = s;
                s = __shfl(wgt[0], j3); wd0 = s; wd1 = s;
            }
            acc0 = fmaf(wa0, va0, acc0); acc1 = fmaf(wa1, va1, acc1);
            acc0 = fmaf(wb0, vb0, acc0); acc1 = fmaf(wb1, vb1, acc1);
            acc0 = fmaf(wc0, vc0, acc0); acc1 = fmaf(wc1, vc1, acc1);
            acc0 = fmaf(wd0, vd0, acc0); acc1 = fmaf(wd1, vd1, acc1);
        }
    } else {
        // ---- generic fallback, 3 passes (rare: d > 64) ----
        float mx[H];
#pragma unroll
        for (int h = 0; h < H; ++h) mx[h] = -INFINITY;
        for (int i = l; i < d; i += 64) {
            int ridx = eix[start + i];
            const bool r1 = (ridx >= N);
            if constexpr (H == 4) {
                float4 kv = *(const float4*)&kj[(size_t)ridx * 4];
                float kk[4] = {kv.x, kv.y, kv.z, kv.w};
#pragma unroll
                for (int h = 0; h < 4; ++h) {
                    float av = (r1 ? q1[h] : q0[h]) + kk[h];
                    av = (av >= 0.f) ? av : 0.2f * av;
                    mx[h] = fmaxf(mx[h], av);
                }
            } else {
                float kv = kj[ridx];
                float av = (r1 ? q1[0] : q0[0]) + kv;
                av = (av >= 0.f) ? av : 0.2f * av;
                mx[0] = fmaxf(mx[0], av);
            }
        }
#pragma unroll
        for (int m = 1; m < 64; m <<= 1)
#pragma unroll
            for (int h = 0; h < H; ++h) mx[h] = fmaxf(mx[h], __shfl_xor(mx[h], m));
        float sm[H];
#pragma unroll
        for (int h = 0; h < H; ++h) sm[h] = 0.f;
        for (int i = l; i < d; i += 64) {
            int ridx = eix[start + i];
            const bool r1 = (ridx >= N);
            if constexpr (H == 4) {
                float4 kv = *(const float4*)&kj[(size_t)ridx * 4];
                float kk[4] = {kv.x, kv.y, kv.z, kv.w};
#pragma unroll
                for (int h = 0; h < 4; ++h) {
                    float av = (r1 ? q1[h] : q0[h]) + kk[h];
                    av = (av >= 0.f) ? av : 0.2f * av;
                    sm[h] += __expf(av - mx[h]);
                }
            } else {
                float kv = kj[ridx];
                float av = (r1 ? q1[0] : q0[0]) + kv;
                av = (av >= 0.f) ? av : 0.2f * av;
                sm[0] += __expf(av - mx[0]);
            }
        }
#pragma unroll
        for (int m = 1; m < 64; m <<= 1)
#pragma unroll
            for (int h = 0; h < H; ++h) sm[h] += __shfl_xor(sm[h], m);
        float rden[H];
#pragma unroll
        for (int h = 0; h < H; ++h) rden[h] = 1.f / (sm[h] + 1e-16f);

        // per-lane head-selected scalars (no runtime register-array indexing)
        float q0h0, q1h0, q0h1, q1h1, mxh0, mxh1, rdh0, rdh1;
        if constexpr (H == 4) {
            q0h0 = (h0 & 1) ? q0[1] : q0[0];  q1h0 = (h0 & 1) ? q1[1] : q1[0];
            q0h1 = (h1 & 1) ? q0[3] : q0[2];  q1h1 = (h1 & 1) ? q1[3] : q1[2];
            mxh0 = (h0 & 1) ? mx[1] : mx[0];  mxh1 = (h1 & 1) ? mx[3] : mx[2];
            rdh0 = (h0 & 1) ? rden[1] : rden[0];
            rdh1 = (h1 & 1) ? rden[3] : rden[2];
        } else {
            q0h0 = q0[0]; q1h0 = q1[0]; q0h1 = q0[0]; q1h1 = q1[0];
            mxh0 = mx[0]; mxh1 = mx[0]; rdh0 = rden[0]; rdh1 = rden[0];
        }
        for (int i = 0; i < d; ++i) {
            int ridx = eix[start + i];          // wave-uniform broadcast
            const bool r1 = (ridx >= N);
            float kh0, kh1;
            if constexpr (H == 4) {
                float4 kv = *(const float4*)&kj[(size_t)ridx * 4];
                kh0 = (h0 & 1) ? kv.y : kv.x;
                kh1 = (h1 & 1) ? kv.w : kv.z;
            } else {
                float kv = kj[ridx];
                kh0 = kv; kh1 = kv;
            }
            float a0 = (r1 ? q1h0 : q0h0) + kh0;
            a0 = (a0 >= 0.f) ? a0 : 0.2f * a0;
            float a1 = (r1 ? q1h1 : q0h1) + kh1;
            a1 = (a1 >= 0.f) ? a1 : 0.2f * a1;
            float w0 = __expf(a0 - mxh0) * rdh0;
            float w1 = __expf(a1 - mxh1) * rdh1;
            const float* row = xw + (size_t)ridx * 128;
            acc0 = fmaf(w0, row[c0], acc0);
            acc1 = fmaf(w1, row[c1], acc1);
        }
    }
    out[(size_t)n * 128 + c0] = acc0 + b0;
    out[(size_t)n * 128 + c1] = acc1 + b1;
}

// ---------------------------------------------------------------------------
extern "C" void kernel_launch(void* const* d_in, const int* in_sizes, int n_in,
                              void* d_out, int out_size, void* d_ws, size_t ws_size,
                              hipStream_t stream)
{
    const float* des   = (const float*)d_in[0];
    const float* tweet = (const float*)d_in[1];
    const float* nump  = (const float*)d_in[2];
    const float* catp  = (const float*)d_in[3];
    const float* newf  = (const float*)d_in[4];
    const int*   eidx  = (const int*)d_in[5];
    const int*   etype = (const int*)d_in[6];
    const float* Wd = (const float*)d_in[7],  *bd = (const float*)d_in[8];
    const float* Wt = (const float*)d_in[9],  *bt = (const float*)d_in[10];
    const float* Wn = (const float*)d_in[11], *bn = (const float*)d_in[12];
    const float* Wc = (const float*)d_in[13], *bc = (const float*)d_in[14];
    const float* Wf = (const float*)d_in[15], *bf = (const float*)d_in[16];
    const float* Wi = (const float*)d_in[17], *bi = (const float*)d_in[18];
    const float* w1 = (const float*)d_in[19], *q1 = (const float*)d_in[20];
    const float* k1 = (const float*)d_in[21], *b1 = (const float*)d_in[22];
    const float* w2 = (const float*)d_in[23], *q2 = (const float*)d_in[24];
    const float* k2 = (const float*)d_in[25], *b2 = (const float*)d_in[26];
    const float* Wo1 = (const float*)d_in[27], *bo1 = (const float*)d_in[28];
    const float* Wo2 = (const float*)d_in[29], *bo2 = (const float*)d_in[30];

    const int N = in_sizes[4];   // new_feature is [N,1]
    const int E = in_sizes[6];   // edge_type is [E]
    const int* esrc = eidx;      // edge_index[0]
    const int* edst = eidx + E;  // edge_index[1]

    // workspace carve-out (all 256B-aligned); ~109 MB total
    char* wsp = (char*)d_ws;
    size_t o = 0;
    auto alloc = [&](size_t bytes) -> char* {
        char* p = wsp + o;
        o = (o + bytes + 255) & ~(size_t)255;
        return p;
    };
    float* xA   = (float*)alloc((size_t)N * 128 * 4);
    float* xB   = (float*)alloc((size_t)N * 128 * 4);
    float* xw   = (float*)alloc((size_t)2 * N * 128 * 4);
    float* qi   = (float*)alloc((size_t)2 * N * 4 * 4);
    float* kj   = (float*)alloc((size_t)2 * N * 4 * 4);
    int*   off  = (int*)alloc((size_t)(N + 1) * 4);
    int*   cur  = (int*)alloc((size_t)N * 4);   // counts, then fill cursor
    int*   eix  = (int*)alloc((size_t)E * 4);
    const int nb = (N + 2047) / 2048;
    int*   bsum = (int*)alloc((size_t)nb * 4);
    int*   bpre = (int*)alloc((size_t)nb * 4);

    const int gM  = (N + 63) / 64;
    const int gE  = (E + 255) / 256;
    const int gN4 = (N + 3) / 4;
    const int gW2 = (2 * N + 3) / 4;

    // 1) feature linears -> xA (columns 0,28,64,76,116)
    gemm_lrelu_k<28, 4><<<gM, 256, 0, stream>>>(des,   768, N, Wd, bd, xA, 128, 0);
    gemm_lrelu_k<36, 4><<<gM, 256, 0, stream>>>(tweet, 768, N, Wt, bt, xA, 128, 28);
    gemm_lrelu_k<12, 4><<<gM, 256, 0, stream>>>(nump,  7,   N, Wn, bn, xA, 128, 64);
    gemm_lrelu_k<40, 4><<<gM, 256, 0, stream>>>(catp,  11,  N, Wc, bc, xA, 128, 76);
    gemm_lrelu_k<12, 4><<<gM, 256, 0, stream>>>(newf,  1,   N, Wf, bf, xA, 128, 116);
    // 2) input linear -> xB
    gemm_lrelu_k<128, 8><<<gM, 256, 0, stream>>>(xA, 128, N, Wi, bi, xB, 128, 0);

    // 3) CSR (dst-sorted packed edge indices); rebuilt every call.
    //    cur holds counts, is scanned IN PLACE into the fill cursor.
    hipMemsetAsync(cur, 0, (size_t)N * 4, stream);
    count_kernel<<<gE, 256, 0, stream>>>(edst, cur, E);
    scan_bsum_k<<<nb, 256, 0, stream>>>(cur, bsum, N);
    scan_top_k<<<1, 256, 0, stream>>>(bsum, bpre, nb, off, N);
    scan_write_k<<<nb, 256, 0, stream>>>(cur, bpre, off, cur, N);
    fill_kernel<<<gE, 256, 0, stream>>>(esrc, edst, etype, cur, eix, N, E);

    // 4) RGAT layer 1 (H=4, C=32): xB -> xA
    gemm_dual_k<<<gM, 512, 0, stream>>>(xB, N, w1, w1 + 16384, xw, xw + (size_t)N * 128);
    qk_kernel<4><<<gW2, 256, 0, stream>>>(xw, q1, k1, qi, kj, N);
    rgat_node_kernel<4, 32><<<gN4, 256, 0, stream>>>(xw, qi, kj, off, eix, b1, xA, N);

    // 5) RGAT layer 2 (H=1, C=128): xA -> xB
    gemm_dual_k<<<gM, 512, 0, stream>>>(xA, N, w2, w2 + 16384, xw, xw + (size_t)N * 128);
    qk_kernel<1><<<gW2, 256, 0, stream>>>(xw, q2, k2, qi, kj, N);
    rgat_node_kernel<1, 128><<<gN4, 256, 0, stream>>>(xw, qi, kj, off, eix, b2, xB, N);

    // 6) fused output linears -> d_out [N,2]
    gemm_out_k<<<gM, 256, 0, stream>>>(xB, N, Wo1, bo1, Wo2, bo2, (float*)d_out);
}